// Round 8
// baseline (5760.149 us; speedup 1.0000x reference)
//
#include <hip/hip_runtime.h>
#include <hip/hip_bf16.h>
#include <stdint.h>

typedef short short8 __attribute__((ext_vector_type(8)));
typedef float f32x4  __attribute__((ext_vector_type(4)));
typedef float fvec4  __attribute__((ext_vector_type(4)));

#define SCOPE_AGENT __HIP_MEMORY_SCOPE_AGENT
#define MFMA(a,b,c) __builtin_amdgcn_mfma_f32_16x16x32_bf16((a),(b),(c),0,0,0)

constexpr int nB = 64, nT = 1024, nD = 256, nH = 512, nO = 256;
constexpr int SLOT_ELEMS = 64 * 1024;                 // 64 rows x (512 hi | 512 lo) bf16
constexpr size_t SLOT_BYTES = (size_t)SLOT_ELEMS * 2; // 128 KiB
constexpr size_t RING_OFF = 4096;
constexpr int NEG = -0x40000000;

// R7 post-mortem: VGPR_Count=168 < the 256 VGPRs of declared L1 weights ->
// per-step scratch reloads inside the recurrence; plus L1 serialized two LLC
// round-trips (h2 then h1). This round: (a) drop W-lo compensation (weights
// hi-only bf16; h and x keep hi+lo) -> halves weight regs, -1/3 MFMAs;
// (b) amdgpu_waves_per_eu(1,1) so the allocator may use up to 512 VGPRs;
// (c) hoist ALL L1 h-loads to right after the poll (one RT, not two);
// (d) 2 accumulator chains per gate (dependent-chain depth 16 -> 8).
#define K4(M)  M(0) M(1) M(2) M(3)
#define GK2(M) M(0,0) M(1,0) M(2,0) M(3,0) M(0,1) M(1,1) M(2,1) M(3,1)
#define GK4(M) GK2(M) M(0,2) M(1,2) M(2,2) M(3,2) M(0,3) M(1,3) M(2,3) M(3,3)

__device__ __forceinline__ float sigm(float x){ return 1.f/(1.f + __expf(-x)); }

// fp32 -> hi bf16 only (weights)
__device__ __forceinline__ short8 cvt8h(const float* p){
  fvec4 a = *(const fvec4*)p;
  fvec4 b = *(const fvec4*)(p + 4);
  short8 hi;
  #pragma unroll
  for (int j = 0; j < 8; j++){
    float v = (j < 4) ? a[j] : b[j-4];
    hi[j] = (short)__bfloat16_as_ushort(__float2bfloat16(v));
  }
  return hi;
}

// fp32 -> (hi, lo) bf16 pair (x input)
__device__ __forceinline__ void cvt8(const float* p, short8& hi, short8& lo){
  fvec4 a = *(const fvec4*)p;
  fvec4 b = *(const fvec4*)(p + 4);
  #pragma unroll
  for (int j = 0; j < 8; j++){
    float v = (j < 4) ? a[j] : b[j-4];
    __hip_bfloat16 h = __float2bfloat16(v);
    float r = v - __bfloat162float(h);
    hi[j] = (short)__bfloat16_as_ushort(h);
    lo[j] = (short)__bfloat16_as_ushort(__float2bfloat16(r));
  }
}

__device__ __forceinline__ unsigned pack2(float a, float b){
  unsigned ha = __bfloat16_as_ushort(__float2bfloat16(a));
  unsigned hb = __bfloat16_as_ushort(__float2bfloat16(b));
  return ha | (hb << 16);
}
__device__ __forceinline__ unsigned pack2lo(float a, float b){
  float ra = a - __bfloat162float(__float2bfloat16(a));
  float rb = b - __bfloat162float(__float2bfloat16(b));
  return pack2(ra, rb);
}

// agent-scope RELAXED (LLC-coherent, fence-free) 16B load
__device__ __forceinline__ short8 aload16(const short* p){
  union { unsigned long long u[2]; short8 v; } r;
  const unsigned long long* q = (const unsigned long long*)p;
  r.u[0] = __hip_atomic_load(q,     __ATOMIC_RELAXED, SCOPE_AGENT);
  r.u[1] = __hip_atomic_load(q + 1, __ATOMIC_RELAXED, SCOPE_AGENT);
  return r.v;
}

// Wave 0 polls 64 flags (lanes 0..31: layer-0, 32..63: layer-1); waves 1-3
// park at the barrier. Fence-free: data moves via relaxed agent atomics.
__device__ __forceinline__ void poll(const int* fb, int t0, int t1){
  if (threadIdx.x < 64){
    int lid = threadIdx.x;
    int tgt = (lid < 32) ? t0 : t1;
    const int* p = fb + lid;
    int spins = 0;
    for(;;){
      int v = __hip_atomic_load(p, __ATOMIC_RELAXED, SCOPE_AGENT);
      if (__all(v >= tgt)) break;
      if (++spins > (1<<17)) break;                // fail-safe, never hang
      if (spins > 64) __builtin_amdgcn_s_sleep(1);
    }
  }
  __syncthreads();
}

__global__ __launch_bounds__(256, 1)
__attribute__((amdgpu_waves_per_eu(1, 1)))
void lstm_kernel(
    const float* __restrict__ x,
    const float* __restrict__ Wih0, const float* __restrict__ Whh0,
    const float* __restrict__ bih0, const float* __restrict__ bhh0,
    const float* __restrict__ Wih1, const float* __restrict__ Whh1,
    const float* __restrict__ bih1, const float* __restrict__ bhh1,
    const float* __restrict__ fcw, const float* __restrict__ fcb,
    float* __restrict__ out,
    short* __restrict__ h1r, short* __restrict__ h2r,
    float* __restrict__ h2last, int* __restrict__ flags)
{
  const int bid   = blockIdx.x;
  const int layer = bid & 1;
  const int bs    = (bid >> 1) & 3;   // batch slice (16 rows)
  const int ns    = bid >> 3;         // H-chunk (16 cols)
  const int tid   = threadIdx.x;
  const int w     = tid >> 6;         // wave = K-quarter owner
  const int l     = tid & 63;
  const int lm    = l & 15;
  const int ke    = (l >> 4) << 3;    // k offset within K=32 step
  const int kw4   = w << 2;           // wave's kk base, H (K=512 -> 16 kk / 4)
  const int kw2   = w << 1;           // wave's kk base, x (K=256 -> 8 kk / 4)

  int* fb     = flags + (bs << 6);
  int* myflag = fb + (layer << 5) + ns;

  // [wave][gate][row][col+pad]: pad 17 kills the 4-way write conflict
  __shared__ float glds[4][4][16][17];

  #define GCOL(g) ((g<<9) + (ns<<4) + lm)     // weight row for gate g
  const int brow = (bs << 4) + lm;            // batch row (A fragment)
  const int bl   = tid >> 4, jj = tid & 15;   // per-thread cell (row, col)
  const int hcolbase = ns << 4;

  float c_reg = 0.f;
  float bia0, bia1, bia2, bia3;
  {
    const float* bi = layer ? bih1 : bih0;
    const float* bh = layer ? bhh1 : bhh0;
    int c0 = (ns<<4) + jj;
    bia0 = bi[c0]      + bh[c0];
    bia1 = bi[512+c0]  + bh[512+c0];
    bia2 = bi[1024+c0] + bh[1024+c0];
    bia3 = bi[1536+c0] + bh[1536+c0];
  }

  // ---- cell update: LDS-reduce wave partials p0..p3 -> c,h -> ring -> flag --
  #define GWR(g) { _Pragma("unroll")                                            \
    for (int r = 0; r < 4; r++) glds[w][g][((l>>4)<<2)+r][lm] = p##g[r]; }
  #define CELLX(SLOTBASE, T, LAST)                                              \
  {                                                                             \
    GWR(0) GWR(1) GWR(2) GWR(3)                                                 \
    __syncthreads();                                                            \
    float gi = glds[0][0][bl][jj]+glds[1][0][bl][jj]+glds[2][0][bl][jj]+glds[3][0][bl][jj]+bia0; \
    float gf = glds[0][1][bl][jj]+glds[1][1][bl][jj]+glds[2][1][bl][jj]+glds[3][1][bl][jj]+bia1; \
    float gg = glds[0][2][bl][jj]+glds[1][2][bl][jj]+glds[2][2][bl][jj]+glds[3][2][bl][jj]+bia2; \
    float go = glds[0][3][bl][jj]+glds[1][3][bl][jj]+glds[2][3][bl][jj]+glds[3][3][bl][jj]+bia3; \
    float cn = sigm(gf)*c_reg + sigm(gi)*tanhf(gg);                             \
    c_reg = cn;                                                                 \
    float hn  = sigm(go)*tanhf(cn);                                             \
    float hn2 = __shfl_down(hn, 1);                                             \
    if (!(jj & 1)){                                                             \
      short* p = (SLOTBASE) + bl*1024 + hcolbase + jj;                          \
      __hip_atomic_store((unsigned*)p,       pack2(hn,hn2),   __ATOMIC_RELAXED, SCOPE_AGENT); \
      __hip_atomic_store((unsigned*)(p+512), pack2lo(hn,hn2), __ATOMIC_RELAXED, SCOPE_AGENT); \
    }                                                                           \
    if (LAST)                                                                   \
      __hip_atomic_store(h2last + (size_t)((bs<<4)+bl)*nH + hcolbase + jj, hn,  \
                         __ATOMIC_RELAXED, SCOPE_AGENT);                        \
    __syncthreads();  /* compiler drains vmcnt(0) before s_barrier */           \
    if (tid == 0)                                                               \
      __hip_atomic_store(myflag, (T), __ATOMIC_RELAXED, SCOPE_AGENT);           \
  }

  if (layer == 0){
    // hi-only weights: x 8 short8 (32 VGPR) + h 16 short8 (64 VGPR)
    #define DWX(g,i) short8 wxh##g##_##i;
    GK2(DWX)
    #define LWX(g,i) wxh##g##_##i = cvt8h(Wih0 + (size_t)GCOL(g)*nD + (kw2+i)*32 + ke);
    GK2(LWX)
    #define DWH(g,i) short8 whh##g##_##i;
    GK4(DWH)
    #define LWH(g,i) whh##g##_##i = cvt8h(Whh0 + (size_t)GCOL(g)*nH + (kw4+i)*32 + ke);
    GK4(LWH)

    // x-projection for t=0 (wave's K-slice only; x hi+lo vs W hi)
    f32x4 xc0={0,0,0,0}, xc1={0,0,0,0}, xc2={0,0,0,0}, xc3={0,0,0,0};
    {
      const float* xb = x + ((size_t)brow*nT + 0)*nD + ke;
      #define XL0(i) short8 xth##i, xtl##i; cvt8(xb + (kw2+i)*32, xth##i, xtl##i);
      XL0(0) XL0(1)
      #define XM0(g,i) xc##g = MFMA(xth##i, wxh##g##_##i, xc##g);               \
                       xc##g = MFMA(xtl##i, wxh##g##_##i, xc##g);
      GK2(XM0)
    }

    for (int t = 0; t < nT; t++){
      poll(fb, t-1, t-8);                       // L0 peers t-1; L1 ring backpressure
      const short* hb = h1r + (size_t)((t+7)&7)*SLOT_ELEMS + brow*1024;
      // wave's K-quarter of h1[t-1]: 8 x 16B
      #define HLD0(i) short8 vh##i = aload16(hb + (kw4+i)*32 + ke);             \
                      short8 vl##i = aload16(hb + 512 + (kw4+i)*32 + ke);
      K4(HLD0)
      // x-projection for t+1 overlaps the LLC latency of the h loads
      f32x4 xn0={0,0,0,0}, xn1={0,0,0,0}, xn2={0,0,0,0}, xn3={0,0,0,0};
      if (t + 1 < nT){
        const float* xb = x + ((size_t)brow*nT + (t+1))*nD + ke;
        #define XLN(i) short8 nxh##i, nxl##i; cvt8(xb + (kw2+i)*32, nxh##i, nxl##i);
        XLN(0) XLN(1)
        #define XMN(g,i) xn##g = MFMA(nxh##i, wxh##g##_##i, xn##g);             \
                         xn##g = MFMA(nxl##i, wxh##g##_##i, xn##g);
        GK2(XMN)
      }
      // h MFMAs: 4 gates x 4 kk x 2 (h-hi + h-lo) = 32/wave, 2 chains/gate
      f32x4 p0a=xc0, p1a=xc1, p2a=xc2, p3a=xc3;
      f32x4 p0b={0,0,0,0}, p1b={0,0,0,0}, p2b={0,0,0,0}, p3b={0,0,0,0};
      #define HMM0(g,i) { f32x4& d = (i<2) ? p##g##a : p##g##b;                 \
        d = MFMA(vh##i, whh##g##_##i, d); d = MFMA(vl##i, whh##g##_##i, d); }
      GK4(HMM0)
      f32x4 p0=p0a+p0b, p1=p1a+p1b, p2=p2a+p2b, p3=p3a+p3b;
      CELLX(h1r + (size_t)(t&7)*SLOT_ELEMS + (bs<<4)*1024, t, 0)
      xc0 = xn0; xc1 = xn1; xc2 = xn2; xc3 = xn3;
    }
  } else {
    // hi-only weights: Whh1 16 short8 + Wih1 16 short8 = 128 VGPR
    #define DWA(g,i) short8 ahh##g##_##i;
    GK4(DWA)
    #define LWA(g,i) ahh##g##_##i = cvt8h(Whh1 + (size_t)GCOL(g)*nH + (kw4+i)*32 + ke);
    GK4(LWA)
    #define DWB(g,i) short8 bwh##g##_##i;
    GK4(DWB)
    #define LWB(g,i) bwh##g##_##i = cvt8h(Wih1 + (size_t)GCOL(g)*nH + (kw4+i)*32 + ke);
    GK4(LWB)

    for (int t = 0; t < nT; t++){
      poll(fb, t, t-1);                         // merged: L0>=t AND own peers>=t-1
      const short* h2b = h2r + (size_t)((t+3)&3)*SLOT_ELEMS + brow*1024;
      const short* h1b = h1r + (size_t)(t&7)*SLOT_ELEMS + brow*1024;
      // hoist ALL loads (h2 and h1) -> single LLC round-trip
      #define HLD2(i) short8 u2h##i = aload16(h2b + (kw4+i)*32 + ke);           \
                      short8 u2l##i = aload16(h2b + 512 + (kw4+i)*32 + ke);
      K4(HLD2)
      #define HLD1(i) short8 u1h##i = aload16(h1b + (kw4+i)*32 + ke);           \
                      short8 u1l##i = aload16(h1b + 512 + (kw4+i)*32 + ke);
      K4(HLD1)
      f32x4 p0a={0,0,0,0}, p1a={0,0,0,0}, p2a={0,0,0,0}, p3a={0,0,0,0};
      f32x4 p0b={0,0,0,0}, p1b={0,0,0,0}, p2b={0,0,0,0}, p3b={0,0,0,0};
      #define HMM2(g,i) { f32x4& d = (i<2) ? p##g##a : p##g##b;                 \
        d = MFMA(u2h##i, ahh##g##_##i, d); d = MFMA(u2l##i, ahh##g##_##i, d); }
      GK4(HMM2)
      #define HMM1(g,i) { f32x4& d = (i<2) ? p##g##a : p##g##b;                 \
        d = MFMA(u1h##i, bwh##g##_##i, d); d = MFMA(u1l##i, bwh##g##_##i, d); }
      GK4(HMM1)
      f32x4 p0=p0a+p0b, p1=p1a+p1b, p2=p2a+p2b, p3=p3a+p3b;
      CELLX(h2r + (size_t)(t&3)*SLOT_ELEMS + (bs<<4)*1024, t, (t == nT-1))
    }

    // final FC in fp32 VALU: out = h2last @ fc_w^T + fc_b (blocks ns<16)
    if (ns < 16){
      poll(fb, NEG, nT-1);
      const int orow = (bs<<4) + bl;
      const int ocol = (ns<<4) + jj;
      const unsigned long long* hq = (const unsigned long long*)(h2last + (size_t)orow*nH);
      const float* wr = fcw + (size_t)ocol*nH;
      float s0=0.f, s1=0.f, s2=0.f, s3=0.f;
      #pragma unroll 8
      for (int k = 0; k < nH; k += 8){
        union{ unsigned long long u; float f[2]; } q0,q1,q2,q3;
        q0.u = __hip_atomic_load(hq + (k>>1)    , __ATOMIC_RELAXED, SCOPE_AGENT);
        q1.u = __hip_atomic_load(hq + (k>>1) + 1, __ATOMIC_RELAXED, SCOPE_AGENT);
        q2.u = __hip_atomic_load(hq + (k>>1) + 2, __ATOMIC_RELAXED, SCOPE_AGENT);
        q3.u = __hip_atomic_load(hq + (k>>1) + 3, __ATOMIC_RELAXED, SCOPE_AGENT);
        fvec4 w0 = *(const fvec4*)(wr + k);
        fvec4 w1 = *(const fvec4*)(wr + k + 4);
        s0 += q0.f[0]*w0[0] + q0.f[1]*w0[1];
        s1 += q1.f[0]*w0[2] + q1.f[1]*w0[3];
        s2 += q2.f[0]*w1[0] + q2.f[1]*w1[1];
        s3 += q3.f[0]*w1[2] + q3.f[1]*w1[3];
      }
      out[(size_t)orow*nO + ocol] = s0 + s1 + s2 + s3 + fcb[ocol];
    }
  }
}

extern "C" void kernel_launch(void* const* d_in, const int* in_sizes, int n_in,
                              void* d_out, int out_size, void* d_ws, size_t ws_size,
                              hipStream_t stream)
{
  char* ws = (char*)d_ws;
  int*   flags  = (int*)ws;
  short* h1r    = (short*)(ws + RING_OFF);                 // 8 slots
  short* h2r    = h1r + 8ull * SLOT_ELEMS;                 // 4 slots
  float* h2last = (float*)((char*)(h2r + 4ull * SLOT_ELEMS));

  hipMemsetAsync(ws, 0xFF, 4*64*sizeof(int), stream);            // flags = -1
  hipMemsetAsync(h1r + 7ull*SLOT_ELEMS, 0, SLOT_BYTES, stream);  // h1[-1] = 0 (slot 7)
  hipMemsetAsync(h2r + 3ull*SLOT_ELEMS, 0, SLOT_BYTES, stream);  // h2[-1] = 0 (slot 3)

  const float* x    = (const float*)d_in[0];
  const float* Wih0 = (const float*)d_in[1];
  const float* Whh0 = (const float*)d_in[2];
  const float* bih0 = (const float*)d_in[3];
  const float* bhh0 = (const float*)d_in[4];
  const float* Wih1 = (const float*)d_in[5];
  const float* Whh1 = (const float*)d_in[6];
  const float* bih1 = (const float*)d_in[7];
  const float* bhh1 = (const float*)d_in[8];
  const float* fcw  = (const float*)d_in[9];
  const float* fcb  = (const float*)d_in[10];
  float* out = (float*)d_out;

  lstm_kernel<<<256, 256, 0, stream>>>(x, Wih0, Whh0, bih0, bhh0,
      Wih1, Whh1, bih1, bhh1, fcw, fcb, out, h1r, h2r, h2last, flags);
}

// Round 10
// 4546.091 us; speedup vs baseline: 1.2671x; 1.2671x over previous
//
#include <hip/hip_runtime.h>
#include <hip/hip_bf16.h>
#include <stdint.h>

typedef short short8 __attribute__((ext_vector_type(8)));
typedef float f32x4  __attribute__((ext_vector_type(4)));
typedef float fvec4  __attribute__((ext_vector_type(4)));

#define SCOPE_AGENT __HIP_MEMORY_SCOPE_AGENT
#define MFMA(a,b,c) __builtin_amdgcn_mfma_f32_16x16x32_bf16((a),(b),(c),0,0,0)

constexpr int nT = 1024, nD = 256, nH = 512, nO = 256;
constexpr int SLOT_ELEMS = 64 * 1024;                 // 64 rows x (512 hi | 512 lo) bf16
constexpr size_t SLOT_BYTES = (size_t)SLOT_ELEMS * 2; // 128 KiB
constexpr size_t RING_OFF = 8192;
constexpr int NEG = -0x40000000;

// R9 post-mortem: sc0 (SE scope) degrades to CU scope on gfx9xx -> consumer
// polls hit their own stale L1 forever (26s guard-break run, absmax 5.8e-2).
// R10: revert to the proven R8 body; attack the h-path LLC service ceiling
// (~12MB/step of cache-bypassing atomic loads ~= 2.2TB/s ~= the 5.5us floor):
//   - consumers use PLAIN cached short8 loads (first reader fills XCD L2,
//     ~31 others L2-hit -> LLC traffic /8, latency ~200cy for most)
//   - staleness bounded by construction: 32-slot rings (reuse distance 32)
//     + buffer_inv (acquire fence) every 16 steps < reuse period
//   - poison/cross-replay dirty-line hazard: one-time SEQ_CST fence
//     (wbl2+inv) + global arrive barrier before any producer store
// Producers/flags unchanged (agent atomics -> LLC authoritative).
#define K4(M)  M(0) M(1) M(2) M(3)
#define GK2(M) M(0,0) M(1,0) M(2,0) M(3,0) M(0,1) M(1,1) M(2,1) M(3,1)
#define GK4(M) GK2(M) M(0,2) M(1,2) M(2,2) M(3,2) M(0,3) M(1,3) M(2,3) M(3,3)

__device__ __forceinline__ float sigm(float x){ return 1.f/(1.f + __expf(-x)); }

// fp32 -> hi bf16 only (weights)
__device__ __forceinline__ short8 cvt8h(const float* p){
  fvec4 a = *(const fvec4*)p;
  fvec4 b = *(const fvec4*)(p + 4);
  short8 hi;
  #pragma unroll
  for (int j = 0; j < 8; j++){
    float v = (j < 4) ? a[j] : b[j-4];
    hi[j] = (short)__bfloat16_as_ushort(__float2bfloat16(v));
  }
  return hi;
}

// fp32 -> (hi, lo) bf16 pair (x input)
__device__ __forceinline__ void cvt8(const float* p, short8& hi, short8& lo){
  fvec4 a = *(const fvec4*)p;
  fvec4 b = *(const fvec4*)(p + 4);
  #pragma unroll
  for (int j = 0; j < 8; j++){
    float v = (j < 4) ? a[j] : b[j-4];
    __hip_bfloat16 h = __float2bfloat16(v);
    float r = v - __bfloat162float(h);
    hi[j] = (short)__bfloat16_as_ushort(h);
    lo[j] = (short)__bfloat16_as_ushort(__float2bfloat16(r));
  }
}

__device__ __forceinline__ unsigned pack2(float a, float b){
  return (unsigned)__bfloat16_as_ushort(__float2bfloat16(a)) |
         ((unsigned)__bfloat16_as_ushort(__float2bfloat16(b)) << 16);
}
__device__ __forceinline__ unsigned pack2lo(float a, float b){
  float ra = a - __bfloat162float(__float2bfloat16(a));
  float rb = b - __bfloat162float(__float2bfloat16(b));
  return pack2(ra, rb);
}

// h load: FAST = plain cached (L2-shareable); slow = agent atomic (R8 proven)
template<int FAST>
__device__ __forceinline__ short8 ldh(const short* p){
  if constexpr (FAST){
    return *(const short8*)p;
  } else {
    union { unsigned long long u[2]; short8 v; } r;
    const unsigned long long* q = (const unsigned long long*)p;
    r.u[0] = __hip_atomic_load(q,     __ATOMIC_RELAXED, SCOPE_AGENT);
    r.u[1] = __hip_atomic_load(q + 1, __ATOMIC_RELAXED, SCOPE_AGENT);
    return r.v;
  }
}

// Wave 0 polls 64 flags (lanes 0..31: layer-0, 32..63: layer-1); waves 1-3
// park at the barrier. Flags are always agent-scope atomics (never cached).
__device__ __forceinline__ void poll(const int* fb, int t0, int t1){
  if (threadIdx.x < 64){
    int lid = threadIdx.x;
    int tgt = (lid < 32) ? t0 : t1;
    const int* p = fb + lid;
    int spins = 0;
    for(;;){
      int v = __hip_atomic_load(p, __ATOMIC_RELAXED, SCOPE_AGENT);
      if (__all(v >= tgt)) break;
      if (++spins > (1<<17)) break;                // fail-safe, never hang
      if (spins > 64) __builtin_amdgcn_s_sleep(1);
    }
  }
  __syncthreads();
}

template<int FAST>
__global__ __launch_bounds__(256, 1)
__attribute__((amdgpu_waves_per_eu(1, 1)))
void lstm_kernel(
    const float* __restrict__ x,
    const float* __restrict__ Wih0, const float* __restrict__ Whh0,
    const float* __restrict__ bih0, const float* __restrict__ bhh0,
    const float* __restrict__ Wih1, const float* __restrict__ Whh1,
    const float* __restrict__ bih1, const float* __restrict__ bhh1,
    const float* __restrict__ fcw, const float* __restrict__ fcb,
    float* __restrict__ out,
    short* __restrict__ h1r, short* __restrict__ h2r,
    float* __restrict__ h2last, int* __restrict__ flags, int* __restrict__ arrive)
{
  constexpr int S1M = FAST ? 31 : 7;   // h1 ring mask (reuse distance 32 / 8)
  constexpr int S2M = FAST ? 31 : 3;   // h2 ring mask
  constexpr int BPS = FAST ? 24 : 8;   // L0->L1 backpressure slack

  const int bid   = blockIdx.x;
  const int layer = bid & 1;
  const int bs    = (bid >> 1) & 3;   // batch slice (16 rows)
  const int ns    = bid >> 3;         // H-chunk (16 cols)
  const int tid   = threadIdx.x;
  const int w     = tid >> 6;         // wave = K-quarter owner
  const int l     = tid & 63;
  const int lm    = l & 15;
  const int ke    = (l >> 4) << 3;    // k offset within K=32 step
  const int kw4   = w << 2;           // wave's kk base, H (16 kk / 4 waves)
  const int kw2   = w << 1;           // wave's kk base, x (8 kk / 4 waves)

  int* fb     = flags + (bs << 6);
  int* myflag = fb + (layer << 5) + ns;

  __shared__ float glds[4][4][16][17];

  // ---- startup scrub: flush+inv every XCD's L2 (poison dirty lines), then
  // global barrier so no producer LLC-store can be clobbered by a late
  // dirty-line writeback from another XCD. arrive is memset 0 per launch.
  __builtin_amdgcn_fence(__ATOMIC_SEQ_CST, "agent");
  __syncthreads();
  if (tid == 0) __hip_atomic_fetch_add(arrive, 1, __ATOMIC_RELAXED, SCOPE_AGENT);
  if (tid < 64){
    int spins = 0;
    while (__hip_atomic_load(arrive, __ATOMIC_RELAXED, SCOPE_AGENT) < 256){
      if (++spins > (1<<20)) break;
      __builtin_amdgcn_s_sleep(1);
    }
  }
  __syncthreads();

  #define GCOL(g) ((g<<9) + (ns<<4) + lm)
  const int brow = (bs << 4) + lm;
  const int bl   = tid >> 4, jj = tid & 15;
  const int hcolbase = ns << 4;

  float c_reg = 0.f;
  float bia0, bia1, bia2, bia3;
  {
    const float* bi = layer ? bih1 : bih0;
    const float* bh = layer ? bhh1 : bhh0;
    int c0 = (ns<<4) + jj;
    bia0 = bi[c0]      + bh[c0];
    bia1 = bi[512+c0]  + bh[512+c0];
    bia2 = bi[1024+c0] + bh[1024+c0];
    bia3 = bi[1536+c0] + bh[1536+c0];
  }

  // ---- cell update: LDS-reduce wave partials p0..p3 -> c,h -> ring -> flag --
  #define GWR(g) { _Pragma("unroll")                                            \
    for (int r = 0; r < 4; r++) glds[w][g][((l>>4)<<2)+r][lm] = p##g[r]; }
  #define CELLX(SLOTBASE, T, LAST)                                              \
  {                                                                             \
    GWR(0) GWR(1) GWR(2) GWR(3)                                                 \
    __syncthreads();                                                            \
    float gi = glds[0][0][bl][jj]+glds[1][0][bl][jj]+glds[2][0][bl][jj]+glds[3][0][bl][jj]+bia0; \
    float gf = glds[0][1][bl][jj]+glds[1][1][bl][jj]+glds[2][1][bl][jj]+glds[3][1][bl][jj]+bia1; \
    float gg = glds[0][2][bl][jj]+glds[1][2][bl][jj]+glds[2][2][bl][jj]+glds[3][2][bl][jj]+bia2; \
    float go = glds[0][3][bl][jj]+glds[1][3][bl][jj]+glds[2][3][bl][jj]+glds[3][3][bl][jj]+bia3; \
    float cn = sigm(gf)*c_reg + sigm(gi)*tanhf(gg);                             \
    c_reg = cn;                                                                 \
    float hn  = sigm(go)*tanhf(cn);                                             \
    float hn2 = __shfl_down(hn, 1);                                             \
    if (!(jj & 1)){                                                             \
      short* p = (SLOTBASE) + bl*1024 + hcolbase + jj;                          \
      __hip_atomic_store((unsigned*)p,       pack2(hn,hn2),   __ATOMIC_RELAXED, SCOPE_AGENT); \
      __hip_atomic_store((unsigned*)(p+512), pack2lo(hn,hn2), __ATOMIC_RELAXED, SCOPE_AGENT); \
    }                                                                           \
    if (LAST)                                                                   \
      __hip_atomic_store(h2last + (size_t)((bs<<4)+bl)*nH + hcolbase + jj, hn,  \
                         __ATOMIC_RELAXED, SCOPE_AGENT);                        \
    __syncthreads();  /* compiler drains vmcnt(0) before s_barrier */           \
    if (tid == 0)                                                               \
      __hip_atomic_store(myflag, (T), __ATOMIC_RELAXED, SCOPE_AGENT);           \
  }

  if (layer == 0){
    // hi-only weights (R8 numerics): x 8 short8 + h 16 short8 per thread
    #define DWX(g,i) short8 wxh##g##_##i;
    GK2(DWX)
    #define LWX(g,i) wxh##g##_##i = cvt8h(Wih0 + (size_t)GCOL(g)*nD + (kw2+i)*32 + ke);
    GK2(LWX)
    #define DWH(g,i) short8 whh##g##_##i;
    GK4(DWH)
    #define LWH(g,i) whh##g##_##i = cvt8h(Whh0 + (size_t)GCOL(g)*nH + (kw4+i)*32 + ke);
    GK4(LWH)

    // x-projection for t=0 (wave's K-slice; x hi+lo vs W hi)
    f32x4 xc0={0,0,0,0}, xc1={0,0,0,0}, xc2={0,0,0,0}, xc3={0,0,0,0};
    {
      const float* xb = x + ((size_t)brow*nT)*nD + ke + kw2*32;
      short8 th0, tl0, th1, tl1;
      cvt8(xb, th0, tl0); cvt8(xb + 32, th1, tl1);
      #define XM0(g,i) xc##g = MFMA(th##i, wxh##g##_##i, xc##g);                \
                       xc##g = MFMA(tl##i, wxh##g##_##i, xc##g);
      GK2(XM0)
    }

    for (int t = 0; t < nT; t++){
      poll(fb, t-1, t-BPS);                     // L0 peers t-1; L1 ring backpressure
      if constexpr (FAST)                        // bounded staleness: inv < reuse
        if ((t & 15) == 0) __builtin_amdgcn_fence(__ATOMIC_ACQUIRE, "agent");
      const short* hb = h1r + (size_t)((t+S1M)&S1M)*SLOT_ELEMS + brow*1024;
      #define HLD0(i) short8 vh##i = ldh<FAST>(hb + (kw4+i)*32 + ke);           \
                      short8 vl##i = ldh<FAST>(hb + 512 + (kw4+i)*32 + ke);
      K4(HLD0)
      // x-projection for t+1 overlaps the h-load latency
      f32x4 xn0={0,0,0,0}, xn1={0,0,0,0}, xn2={0,0,0,0}, xn3={0,0,0,0};
      if (t + 1 < nT){
        const float* xb = x + ((size_t)brow*nT + (t+1))*nD + ke + kw2*32;
        short8 th0, tl0, th1, tl1;
        cvt8(xb, th0, tl0); cvt8(xb + 32, th1, tl1);
        #define XMN(g,i) xn##g = MFMA(th##i, wxh##g##_##i, xn##g);              \
                         xn##g = MFMA(tl##i, wxh##g##_##i, xn##g);
        GK2(XMN)
      }
      // h MFMAs: 4 gates x 4 kk x 2 (h-hi + h-lo), two chains per gate
      f32x4 p0a=xc0, p1a=xc1, p2a=xc2, p3a=xc3;
      f32x4 p0b={0,0,0,0}, p1b={0,0,0,0}, p2b={0,0,0,0}, p3b={0,0,0,0};
      #define HMM0(g,i) { f32x4& d = (i<2) ? p##g##a : p##g##b;                 \
        d = MFMA(vh##i, whh##g##_##i, d); d = MFMA(vl##i, whh##g##_##i, d); }
      GK4(HMM0)
      f32x4 p0=p0a+p0b, p1=p1a+p1b, p2=p2a+p2b, p3=p3a+p3b;
      CELLX(h1r + (size_t)(t&S1M)*SLOT_ELEMS + (bs<<4)*1024, t, 0)
      xc0 = xn0; xc1 = xn1; xc2 = xn2; xc3 = xn3;
    }
  } else {
    // hi-only weights: Whh1 16 + Wih1 16 short8 per thread
    #define DWA(g,i) short8 ahh##g##_##i;
    GK4(DWA)
    #define LWA(g,i) ahh##g##_##i = cvt8h(Whh1 + (size_t)GCOL(g)*nH + (kw4+i)*32 + ke);
    GK4(LWA)
    #define DWB(g,i) short8 bwh##g##_##i;
    GK4(DWB)
    #define LWB(g,i) bwh##g##_##i = cvt8h(Wih1 + (size_t)GCOL(g)*nH + (kw4+i)*32 + ke);
    GK4(LWB)

    for (int t = 0; t < nT; t++){
      poll(fb, t, t-1);                         // L0>=t AND own peers>=t-1
      if constexpr (FAST)
        if ((t & 15) == 0) __builtin_amdgcn_fence(__ATOMIC_ACQUIRE, "agent");
      const short* h2b = h2r + (size_t)((t+S2M)&S2M)*SLOT_ELEMS + brow*1024;
      const short* h1b = h1r + (size_t)(t&S1M)*SLOT_ELEMS + brow*1024;
      // hoist ALL loads (h2 and h1): overlap their latency
      #define HLD2(i) short8 u2h##i = ldh<FAST>(h2b + (kw4+i)*32 + ke);         \
                      short8 u2l##i = ldh<FAST>(h2b + 512 + (kw4+i)*32 + ke);
      K4(HLD2)
      #define HLD1(i) short8 u1h##i = ldh<FAST>(h1b + (kw4+i)*32 + ke);         \
                      short8 u1l##i = ldh<FAST>(h1b + 512 + (kw4+i)*32 + ke);
      K4(HLD1)
      f32x4 p0a={0,0,0,0}, p1a={0,0,0,0}, p2a={0,0,0,0}, p3a={0,0,0,0};
      f32x4 p0b={0,0,0,0}, p1b={0,0,0,0}, p2b={0,0,0,0}, p3b={0,0,0,0};
      #define HMM2(g,i) { f32x4& d = (i<2) ? p##g##a : p##g##b;                 \
        d = MFMA(u2h##i, ahh##g##_##i, d); d = MFMA(u2l##i, ahh##g##_##i, d); }
      GK4(HMM2)
      #define HMM1(g,i) { f32x4& d = (i<2) ? p##g##a : p##g##b;                 \
        d = MFMA(u1h##i, bwh##g##_##i, d); d = MFMA(u1l##i, bwh##g##_##i, d); }
      GK4(HMM1)
      f32x4 p0=p0a+p0b, p1=p1a+p1b, p2=p2a+p2b, p3=p3a+p3b;
      CELLX(h2r + (size_t)(t&S2M)*SLOT_ELEMS + (bs<<4)*1024, t, (t == nT-1))
    }

    // final FC in fp32 VALU (blocks ns<16); h2last via agent (LLC) reads
    if (ns < 16){
      poll(fb, NEG, nT-1);
      const int orow = (bs<<4) + bl;
      const int ocol = (ns<<4) + jj;
      const unsigned long long* hq = (const unsigned long long*)(h2last + (size_t)orow*nH);
      const float* wr = fcw + (size_t)ocol*nH;
      float s0=0.f, s1=0.f, s2=0.f, s3=0.f;
      #pragma unroll 8
      for (int k = 0; k < nH; k += 8){
        union{ unsigned long long u; float f[2]; } q0,q1,q2,q3;
        q0.u = __hip_atomic_load(hq + (k>>1)    , __ATOMIC_RELAXED, SCOPE_AGENT);
        q1.u = __hip_atomic_load(hq + (k>>1) + 1, __ATOMIC_RELAXED, SCOPE_AGENT);
        q2.u = __hip_atomic_load(hq + (k>>1) + 2, __ATOMIC_RELAXED, SCOPE_AGENT);
        q3.u = __hip_atomic_load(hq + (k>>1) + 3, __ATOMIC_RELAXED, SCOPE_AGENT);
        fvec4 w0 = *(const fvec4*)(wr + k);
        fvec4 w1 = *(const fvec4*)(wr + k + 4);
        s0 += q0.f[0]*w0[0] + q0.f[1]*w0[1];
        s1 += q1.f[0]*w0[2] + q1.f[1]*w0[3];
        s2 += q2.f[0]*w1[0] + q2.f[1]*w1[1];
        s3 += q3.f[0]*w1[2] + q3.f[1]*w1[3];
      }
      out[(size_t)orow*nO + ocol] = s0 + s1 + s2 + s3 + fcb[ocol];
    }
  }
}

extern "C" void kernel_launch(void* const* d_in, const int* in_sizes, int n_in,
                              void* d_out, int out_size, void* d_ws, size_t ws_size,
                              hipStream_t stream)
{
  char* ws = (char*)d_ws;
  int* flags  = (int*)ws;                 // 256 ints
  int* arrive = (int*)(ws + 2048);        // 1 int (memset 0 per launch)

  // FAST layout: 32+32 slot rings (8 MiB) + h2last
  size_t need_fast = RING_OFF + 64ull*SLOT_BYTES + (size_t)64*512*4 + 4096;
  const int fast = (ws_size >= need_fast) ? 1 : 0;
  const int s1 = fast ? 32 : 8, s2 = fast ? 32 : 4;

  short* h1r = (short*)(ws + RING_OFF);
  short* h2r = h1r + (size_t)s1 * SLOT_ELEMS;
  float* h2last = (float*)(h2r + (size_t)s2 * SLOT_ELEMS);

  hipMemsetAsync(ws, 0xFF, 1024, stream);                               // flags = -1
  hipMemsetAsync(ws + 2048, 0, 64, stream);                             // arrive = 0
  hipMemsetAsync(h1r + (size_t)(s1-1)*SLOT_ELEMS, 0, SLOT_BYTES, stream); // h1[-1]
  hipMemsetAsync(h2r + (size_t)(s2-1)*SLOT_ELEMS, 0, SLOT_BYTES, stream); // h2[-1]

  const float* x    = (const float*)d_in[0];
  const float* Wih0 = (const float*)d_in[1];
  const float* Whh0 = (const float*)d_in[2];
  const float* bih0 = (const float*)d_in[3];
  const float* bhh0 = (const float*)d_in[4];
  const float* Wih1 = (const float*)d_in[5];
  const float* Whh1 = (const float*)d_in[6];
  const float* bih1 = (const float*)d_in[7];
  const float* bhh1 = (const float*)d_in[8];
  const float* fcw  = (const float*)d_in[9];
  const float* fcb  = (const float*)d_in[10];
  float* out = (float*)d_out;

  if (fast)
    lstm_kernel<1><<<256, 256, 0, stream>>>(x, Wih0, Whh0, bih0, bhh0,
        Wih1, Whh1, bih1, bhh1, fcw, fcb, out, h1r, h2r, h2last, flags, arrive);
  else
    lstm_kernel<0><<<256, 256, 0, stream>>>(x, Wih0, Whh0, bih0, bhh0,
        Wih1, Whh1, bih1, bhh1, fcw, fcb, out, h1r, h2r, h2last, flags, arrive);
}